// Round 2
// baseline (270.873 us; speedup 1.0000x reference)
//
#include <hip/hip_runtime.h>
#include <hip/hip_bf16.h>
#include <math.h>

// Problem constants (reference setup_inputs): B=64, Q=16, O=20, D=256,
// NUM_CAT=101, T=4096 (T re-derived from out_size on host).
constexpr int B_ = 64;
constexpr int Q_ = 16;
constexpr int O_ = 20;
constexpr int D_ = 256;

// ---------------------------------------------------------------------------
// Kernel 1: belief[b,q,d] = tanh( sum_o softmax(logits[b,q,:])[o] *
//                                 emb[cat[b,o], d] )   -> d_ws  (1 MiB)
// ---------------------------------------------------------------------------
__global__ __launch_bounds__(D_) void belief_kernel(
    const float* __restrict__ logits,   // [B,Q,O]
    const float* __restrict__ emb,      // [NUM_CAT, D]
    const int*   __restrict__ cats,     // [B,O]
    float*       __restrict__ belief)   // [B,Q,D]
{
    const int bq = blockIdx.x;
    const int b  = bq >> 4;             // Q_ == 16
    const int d  = threadIdx.x;

    __shared__ float s_logit[O_];
    __shared__ int   s_cat[O_];
    if (d < O_) {
        s_logit[d] = logits[bq * O_ + d];
        s_cat[d]   = cats[b * O_ + d];
    }
    __syncthreads();

    float m = -INFINITY;
    #pragma unroll
    for (int o = 0; o < O_; ++o) m = fmaxf(m, s_logit[o]);
    float w[O_];
    float sum = 0.f;
    #pragma unroll
    for (int o = 0; o < O_; ++o) { w[o] = expf(s_logit[o] - m); sum += w[o]; }
    const float inv = 1.f / sum;

    float acc = 0.f;
    #pragma unroll
    for (int o = 0; o < O_; ++o)
        acc = fmaf(w[o] * inv, emb[s_cat[o] * D_ + d], acc);

    belief[bq * D_ + d] = tanhf(acc);
}

// ---------------------------------------------------------------------------
// Kernel 2: expansion, streaming-store optimized.
//   Phase A: stage belief[b] (16 KB) into LDS + one extra ZERO row (row 16).
//   Phase B: each thread computes the LDS byte-offset for one t-row:
//            valid -> qi*1024, invalid -> 16*1024 (zero row). No branches in
//            the hot loop afterwards.
//   Phase C: pure stream: per iter, ds_read_b32 (row offset, wave-broadcast),
//            ds_read_b128 (belief fragment), global_store_dwordx4, ptr += 4KB.
// Grid: (T/ROWS, B) x 256 threads. Wave w handles rows 4k+w (64 rows each).
// ---------------------------------------------------------------------------
constexpr int ROWS_ = 256;

__global__ __launch_bounds__(256) void expand_kernel(
    const float* __restrict__ belief,   // [B,Q,D]
    const int*   __restrict__ cum,      // [B,Q]
    const int*   __restrict__ nq_arr,   // [B]
    float*       __restrict__ out,      // [B,T,D]
    int T)
{
    const int b   = blockIdx.y;
    const int t0  = blockIdx.x * ROWS_;
    const int tid = threadIdx.x;

    __shared__ float s_belief[(Q_ + 1) * D_];   // 17 KB; row Q_ = zeros
    __shared__ int   s_off[ROWS_];              // per-row byte offset

    // Phase A: stage belief[b] (1024 float4 by 256 threads) + zero row.
    {
        const float4* src = (const float4*)(belief + (size_t)b * Q_ * D_);
        float4*       dst = (float4*)s_belief;
        #pragma unroll
        for (int i = 0; i < (Q_ * D_ / 4) / 256; ++i)
            dst[tid + i * 256] = src[tid + i * 256];
        s_belief[Q_ * D_ + tid] = 0.f;
    }

    // Phase B: row -> LDS byte offset (qi*1024, or zero-row for invalid).
    {
        const int nq = nq_arr[b];
        const int t  = t0 + tid;
        int qi = 0;
        #pragma unroll
        for (int j = 1; j < Q_; ++j) {
            const int bnd = (j <= nq - 1) ? (cum[b * Q_ + j] - 1) : 0x7fffffff;
            qi += (t >= bnd) ? 1 : 0;
        }
        const int row = (qi < nq - 1) ? qi : Q_;    // invalid -> zero row
        s_off[tid] = row * (D_ * 4);                // byte offset
    }
    __syncthreads();

    // Phase C: stream 256 rows (4 rows / block-iteration, 1 row / wave).
    const int col  = tid & 63;      // float4 lane within the row
    const int rsub = tid >> 6;      // wave index = row-within-group

    float4* dst = (float4*)(out + ((size_t)b * T + (t0 + rsub)) * D_) + col;
    const char* sb = (const char*)s_belief;
    const int col_b = col << 4;     // byte offset of this lane's fragment

    if (t0 + ROWS_ <= T) {
        #pragma unroll 8
        for (int it = 0; it < ROWS_ / 4; ++it) {
            const int off = s_off[it * 4 + rsub];           // wave-broadcast
            const float4 v = *(const float4*)(sb + off + col_b);
            *dst = v;
            dst += D_;              // 4 rows * D_/4 float4 = D_ float4s
        }
    } else {
        for (int it = 0; it < ROWS_ / 4; ++it) {
            const int t = t0 + it * 4 + rsub;
            if (t < T) {
                const int off = s_off[it * 4 + rsub];
                const float4 v = *(const float4*)(sb + off + col_b);
                *dst = v;
            }
            dst += D_;
        }
    }
}

extern "C" void kernel_launch(void* const* d_in, const int* in_sizes, int n_in,
                              void* d_out, int out_size, void* d_ws, size_t ws_size,
                              hipStream_t stream)
{
    const float* logits = (const float*)d_in[0];   // [B,Q,O] fp32
    const float* emb    = (const float*)d_in[1];   // [101,D] fp32
    const int*   cats   = (const int*)d_in[2];     // [B,O] int32
    const int*   cum    = (const int*)d_in[3];     // [B,Q] int32
    const int*   nq     = (const int*)d_in[4];     // [B] int32

    float* out    = (float*)d_out;
    float* belief = (float*)d_ws;                  // B*Q*D floats = 1 MiB

    const int T = out_size / (B_ * D_);            // 4096

    belief_kernel<<<B_ * Q_, D_, 0, stream>>>(logits, emb, cats, belief);

    dim3 grid((T + ROWS_ - 1) / ROWS_, B_);
    expand_kernel<<<grid, 256, 0, stream>>>(belief, cum, nq, out, T);
}